// Round 12
// baseline (62.447 us; speedup 1.0000x reference)
//
#include <hip/hip_runtime.h>

#define Bc 64
#define Sc 512
#define Dc 768
#define NLc 9
#define Lc 11
#define START (Lc-2)
#define ENDL (Lc-1)
#define NEGC -10000.0f
#define LOG2E 1.4426950408889634f
#define LN2 0.6931471805599453f
#define CHUNK 16
#define NCH (Sc / CHUNK)   // 32
#define WROW 776           // padded bf16 row stride (768+8 shorts)
#define PSTRIDE ((size_t)Bc * Sc * NLc)   // 294912 floats per partial buffer

typedef __attribute__((ext_vector_type(8))) short s16x8;   // 8 bf16 (4 VGPRs)
typedef __attribute__((ext_vector_type(4))) float f32x4;   // 4 fp32 acc

union U4 { float4 f; unsigned int u[4]; };
union R8 { unsigned int w[4]; s16x8 v; };

// pack 8 fp32 -> 8 bf16 (truncation, same as R8 -> same numerics)
static __device__ __forceinline__ s16x8 pack8(float4 lo, float4 hi) {
  U4 L, H; L.f = lo; H.f = hi;
  R8 r;
  r.w[0] = (L.u[1] & 0xFFFF0000u) | (L.u[0] >> 16);
  r.w[1] = (L.u[3] & 0xFFFF0000u) | (L.u[2] >> 16);
  r.w[2] = (H.u[1] & 0xFFFF0000u) | (H.u[0] >> 16);
  r.w[3] = (H.u[3] & 0xFFFF0000u) | (H.u[2] >> 16);
  return r.v;
}

// K1 (MFMA, split-K x4, max occupancy):
// R10/R11 post-mortem: pure x-streams run 6 TB/s in ANY pattern (probes), all
// compute variants stall at ~60us with ~13us of issue work at 8-16 waves/CU.
// Hypothesis: per-wave dependent chains too long for the resident wave count.
// This kernel: 8192 waves (vs R8's 2048), each = 16-row tile x 1/4-K
// (6 MFMA steps, 12 global loads, 6 ds_read_b128). 512-thr blocks,
// (512,6) cap ~85 VGPR (~50 live, no spill), LDS 24.8KB -> 4 blocks/CU.
// Four f32 partial buffers summed downstream in k_chunk/k_batch.
__global__ __launch_bounds__(512, 6) void k_logits(const float* __restrict__ x,
    const float* __restrict__ W, const float* __restrict__ bias,
    float* __restrict__ p0, float* __restrict__ p1,
    float* __restrict__ p2, float* __restrict__ p3)
{
  __shared__ unsigned short Wb[16][WROW];   // 24832 B, rows 9..15 zero
  for (int i = threadIdx.x; i < 16 * 384; i += 512) {
    const int r = i / 384, c = i % 384;     // c = u32 word (2 bf16)
    unsigned int w = 0u;
    if (r < NLc) {
      U4 t; t.f.x = W[r * Dc + 2 * c]; t.f.y = W[r * Dc + 2 * c + 1];
      w = (t.u[1] & 0xFFFF0000u) | (t.u[0] >> 16);
    }
    *reinterpret_cast<unsigned int*>(&Wb[r][2 * c]) = w;
  }
  __syncthreads();

  const int tid  = threadIdx.x;
  const int lane = tid & 63;
  const int wid  = tid >> 6;                // 0..7
  const int tile = blockIdx.x * 2 + (wid >> 2);   // 2048 tiles of 16 rows
  const int h    = wid & 3;                 // K quarter 0..3
  const int R    = tile * 16;
  const int j    = lane & 15;               // A row within tile / B col (label)
  const int kg   = lane >> 4;               // k-group 0..3

  const float* xp = x + (size_t)(R + j) * Dc + h * 192 + kg * 8;
  const unsigned short* wrow = &Wb[j][h * 192 + kg * 8];

  f32x4 acc = {0.f, 0.f, 0.f, 0.f};
  // depth-2 prefetch, named scalars (R5 lesson: arrays -> scratch)
  float4 a0 = *reinterpret_cast<const float4*>(xp);
  float4 a1 = *reinterpret_cast<const float4*>(xp + 4);
  float4 b0 = *reinterpret_cast<const float4*>(xp + 32);
  float4 b1 = *reinterpret_cast<const float4*>(xp + 36);

#pragma unroll
  for (int t = 0; t < 6; ++t) {
    float4 n0, n1;
    if (t < 4) {
      n0 = *reinterpret_cast<const float4*>(xp + 32 * (t + 2));
      n1 = *reinterpret_cast<const float4*>(xp + 32 * (t + 2) + 4);
    }
    const s16x8 afrag = pack8(a0, a1);
    const s16x8 bfrag = *reinterpret_cast<const s16x8*>(wrow + 32 * t);
    acc = __builtin_amdgcn_mfma_f32_16x16x32_bf16(afrag, bfrag, acc, 0, 0, 0);
    a0 = b0; a1 = b1;
    if (t < 4) { b0 = n0; b1 = n1; }
  }

  // C/D store (m89-verified): col=j(label), row=kg*4+r. Bias only in h==0.
  if (j < NLc) {
    float* dst = (h == 0) ? p0 : (h == 1) ? p1 : (h == 2) ? p2 : p3;
    const float bb = (h == 0) ? bias[j] : 0.f;
#pragma unroll
    for (int r = 0; r < 4; ++r) {
      const int row = R + kg * 4 + r;
      dst[(size_t)row * NLc + j] = acc[r] + bb;
    }
  }
}

// Phase 1: per (batch, chunk) 11x11 log-semiring transfer matrix.
// logits = p0+p1+p2+p3 summed at staging. Zeroes k_batch counter (block 0).
__global__ __launch_bounds__(64) void k_chunk(const float* __restrict__ p0,
    const float* __restrict__ p1, const float* __restrict__ p2,
    const float* __restrict__ p3,
    const int* __restrict__ mask, const float* __restrict__ trans,
    float* __restrict__ Mout, unsigned* __restrict__ cnt)
{
  if (blockIdx.x == 0 && threadIdx.x == 0) cnt[0] = 0u;
  const int b = blockIdx.x / NCH;
  const int c = blockIdx.x % NCH;
  const int lane = threadIdx.x;
  __shared__ float Mbuf[2][121];
  __shared__ float Llog[CHUNK][NLc];

  int len = 0;
  for (int t = lane; t < Sc; t += 64) len += mask[b * Sc + t];
#pragma unroll
  for (int off = 32; off >= 1; off >>= 1) len += __shfl_xor(len, off);

  for (int i = lane; i < CHUNK * NLc; i += 64) {
    const int t = i / NLc, l = i % NLc;
    const size_t idx = ((size_t)b * Sc + c * CHUNK + t) * NLc + l;
    Llog[t][l] = p0[idx] + p1[idx] + p2[idx] + p3[idx];
  }
  for (int e = lane; e < 121; e += 64) {
    const int i = e % Lc, j = e / Lc;
    Mbuf[0][e] = (i == j) ? 0.f : NEGC;
  }
  const int e1 = lane;          const bool v1 = (e1 < 121);
  const int e2 = lane + 64;     const bool v2 = (e2 < 121);
  const int i1 = v1 ? (e1 % Lc) : 0, j1 = v1 ? (e1 / Lc) : 0;
  const int i2 = v2 ? (e2 % Lc) : 0, j2 = v2 ? (e2 / Lc) : 0;
  float trow1[Lc], trow2[Lc];
#pragma unroll
  for (int k = 0; k < Lc; k++) {
    trow1[k] = trans[i1 * Lc + k];
    trow2[k] = trans[i2 * Lc + k];
  }
  __syncthreads();

  int p = 0;
  for (int t = 0; t < CHUNK; ++t) {
    const int tg = c * CHUNK + t;
    if (tg < len) {   // uniform across block
      const float lg1 = (i1 < NLc) ? Llog[t][i1] : NEGC;
      const float lg2 = (i2 < NLc) ? Llog[t][i2] : NEGC;
      float terms[Lc];
      float m1 = -3.0e38f;
#pragma unroll
      for (int k = 0; k < Lc; k++) {
        terms[k] = trow1[k] + Mbuf[p][j1 * Lc + k];
        m1 = fmaxf(m1, terms[k]);
      }
      float s1 = 0.f;
#pragma unroll
      for (int k = 0; k < Lc; k++) s1 += exp2f((terms[k] - m1) * LOG2E);
      const float n1 = lg1 + m1 + log2f(s1) * LN2;
      float m2 = -3.0e38f;
#pragma unroll
      for (int k = 0; k < Lc; k++) {
        terms[k] = trow2[k] + Mbuf[p][j2 * Lc + k];
        m2 = fmaxf(m2, terms[k]);
      }
      float s2 = 0.f;
#pragma unroll
      for (int k = 0; k < Lc; k++) s2 += exp2f((terms[k] - m2) * LOG2E);
      const float n2 = lg2 + m2 + log2f(s2) * LN2;
      if (v1) Mbuf[p ^ 1][e1] = n1;
      if (v2) Mbuf[p ^ 1][e2] = n2;
      p ^= 1;
    }
    __syncthreads();
  }
  for (int e = lane; e < 121; e += 64)
    Mout[((size_t)b * NCH + c) * 121 + e] = Mbuf[p][e];
}

// K_batch: wave 0 combine (norm), waves 1-3 unary+binary (logits = sum of
// partials); last block reduces all parts (agent-scope atomics, G16).
__global__ __launch_bounds__(256) void k_batch(const float* __restrict__ p0,
    const float* __restrict__ p1, const float* __restrict__ p2,
    const float* __restrict__ p3,
    const int* __restrict__ mask, const int* __restrict__ labels,
    const float* __restrict__ trans, const float* __restrict__ Min,
    float* __restrict__ part, unsigned* __restrict__ cnt,
    float* __restrict__ out)
{
  const int b = blockIdx.x;
  const int tid = threadIdx.x;
  const int wid = tid >> 6;
  const int lane = tid & 63;
  const int sl = lane & 15;
  __shared__ float Ms[NCH * 121];
  __shared__ int   ls[4];
  __shared__ float fs[4];
  __shared__ int   len_sh;
  __shared__ float norm_sh;
  __shared__ int   do_final;

  {
    const float4* src = reinterpret_cast<const float4*>(Min + (size_t)b * NCH * 121);
    for (int i = tid; i < (NCH * 121) / 4; i += 256)
      reinterpret_cast<float4*>(Ms)[i] = src[i];
  }
  int lp = 0;
  for (int t = tid; t < Sc; t += 256) lp += mask[b * Sc + t];
#pragma unroll
  for (int off = 32; off >= 1; off >>= 1) lp += __shfl_down(lp, off);
  if (lane == 0) ls[wid] = lp;
  __syncthreads();
  if (tid == 0) len_sh = ls[0] + ls[1] + ls[2] + ls[3];
  __syncthreads();
  const int len = len_sh;

  if (wid == 0) {
    const int ii = (sl < Lc) ? sl : 0;
    float alpha = (sl == START) ? 0.f : NEGC;
#pragma unroll 1
    for (int c = 0; c < NCH; ++c) {
      const float* M = Ms + c * 121;
      float terms[Lc];
      float m = -3.0e38f;
#pragma unroll
      for (int k = 0; k < Lc; k++) {
        const float ak = __shfl(alpha, k, 16);
        terms[k] = M[k * Lc + ii] + ak;
        m = fmaxf(m, terms[k]);
      }
      float s = 0.f;
#pragma unroll
      for (int k = 0; k < Lc; k++) s += exp2f((terms[k] - m) * LOG2E);
      const float anew = m + log2f(s) * LN2;
      alpha = (sl < Lc) ? anew : alpha;
    }
    float v = (sl < Lc) ? (alpha + trans[ENDL * Lc + sl]) : -3.0e38f;
    float mm = v;
#pragma unroll
    for (int off = 8; off >= 1; off >>= 1) mm = fmaxf(mm, __shfl_xor(mm, off, 16));
    float se = exp2f((v - mm) * LOG2E);
#pragma unroll
    for (int off = 8; off >= 1; off >>= 1) se += __shfl_xor(se, off, 16);
    if (lane == 0) norm_sh = mm + log2f(se) * LN2;
  } else {
    float u = 0.f;
    for (int t = tid - 64; t < Sc; t += 192)
      if (t < len) {
        const size_t idx = ((size_t)b * Sc + t) * NLc + labels[b * Sc + t];
        u += p0[idx] + p1[idx] + p2[idx] + p3[idx];
      }
    for (int t = tid - 64; t <= Sc; t += 192) {
      if (t <= len) {
        const int cur = (t == 0) ? START : ((t - 1 < len) ? labels[b * Sc + t - 1] : ENDL);
        const int nxt = (t < len) ? labels[b * Sc + t] : ENDL;
        u += trans[nxt * Lc + cur];
      }
    }
#pragma unroll
    for (int off = 32; off >= 1; off >>= 1) u += __shfl_down(u, off);
    if (lane == 0) fs[wid] = u;
  }
  __syncthreads();

  if (tid == 0) {
    const float pb = fs[1] + fs[2] + fs[3] - norm_sh;
    __hip_atomic_store(&part[b], pb, __ATOMIC_RELEASE, __HIP_MEMORY_SCOPE_AGENT);
    const unsigned old = __hip_atomic_fetch_add(cnt, 1u, __ATOMIC_ACQ_REL,
                                                __HIP_MEMORY_SCOPE_AGENT);
    do_final = (old == (unsigned)(Bc - 1)) ? 1 : 0;
  }
  __syncthreads();
  if (do_final && wid == 0) {
    float v = __hip_atomic_load(&part[lane], __ATOMIC_RELAXED,
                                __HIP_MEMORY_SCOPE_AGENT);
#pragma unroll
    for (int off = 32; off >= 1; off >>= 1) v += __shfl_xor(v, off);
    if (lane == 0) out[0] = -v * (1.0f / Bc);
  }
}

extern "C" void kernel_launch(void* const* d_in, const int* in_sizes, int n_in,
                              void* d_out, int out_size, void* d_ws, size_t ws_size,
                              hipStream_t stream)
{
  const float* x      = (const float*)d_in[0];
  const int*   mask   = (const int*)d_in[1];
  const int*   labels = (const int*)d_in[2];
  const float* W      = (const float*)d_in[3];
  const float* bias   = (const float*)d_in[4];
  const float* trans  = (const float*)d_in[5];
  float* out = (float*)d_out;
  float* ws  = (float*)d_ws;

  float*    ws_p0   = ws;                          // 4 partial logit buffers
  float*    ws_p1   = ws_p0 + PSTRIDE;
  float*    ws_p2   = ws_p1 + PSTRIDE;
  float*    ws_p3   = ws_p2 + PSTRIDE;
  float*    ws_M    = ws_p3 + PSTRIDE;             // B*NCH*121 floats
  float*    ws_part = ws_M + (size_t)Bc * NCH * 121;
  unsigned* ws_cnt  = (unsigned*)(ws_part + Bc);

  hipLaunchKernelGGL(k_logits, dim3(1024), dim3(512), 0, stream,
                     x, W, bias, ws_p0, ws_p1, ws_p2, ws_p3);
  hipLaunchKernelGGL(k_chunk,  dim3(Bc * NCH), dim3(64), 0, stream,
                     ws_p0, ws_p1, ws_p2, ws_p3, mask, trans, ws_M, ws_cnt);
  hipLaunchKernelGGL(k_batch,  dim3(Bc), dim3(256), 0, stream,
                     ws_p0, ws_p1, ws_p2, ws_p3, mask, labels, trans, ws_M,
                     ws_part, ws_cnt, out);
}